// Round 8
// baseline (276.139 us; speedup 1.0000x reference)
//
#include <hip/hip_runtime.h>

// FlyHash-style sparse projection + per-row exact top-k threshold.
//
// Round 20 = R19 resubmitted verbatim (bench died on container acquire,
// not on the kernel — same infra signature as R15->R16).
// R19 = R17 champion structure (TPB=1024, grid=1024, ROWS=4, FPT=10,
// rk prefetch, hist + wave bracket scan + list select + fallback) with the
// store path decoupled from the threshold and the barrier-drain tax removed:
//  - ZERO-STREAM: all 40 nontemporal zero-stores issue at kernel start,
//    AFTER the rk/staging loads in program order (vmcnt is FIFO: waits for
//    loads never drain the younger stores). They drain to HBM under phases
//    1-4. After thresholds, scatter only values >= t (~32/row). Same-thread
//    same-address ordering via per-wave s_waitcnt vmcnt(0) (cheap by then).
//    Predicate v >= t with ties == reference jnp.where(x >= thresh). Zeros
//    are 0.0f. Bit-exact.
//  - LGKM-ONLY BARRIERS: the compiler emits vmcnt(0) before every
//    __syncthreads, which would put the zero-store queue on the critical
//    path at the first barrier (R16's failure mode). Every main-path
//    barrier's cross-thread deps are LDS-only (staging ds_write, hist
//    atomics, sh_* state), so use s_waitcnt lgkmcnt(0) + raw s_barrier.
//    Post-barrier consumers are ds_read ops (memory), so the inline-asm
//    hoist hazard (rule 18) does not apply. Phase-4 fallback keeps
//    __syncthreads (rare path, correctness first).
// Chunking (R15/16/18) abandoned: 3 attempts all lost to the champion's
// free cross-block overlap (stores drain past s_endpgm under the next
// block's compute). Bit-exactness (absmax 0, R2-R18): serial f32 fold-left
// ascending == ref einsum; threshold = an actual x value's bit pattern.

typedef float f4 __attribute__((ext_vector_type(4)));

constexpr int IN_F   = 512;
constexpr int OUT_F  = 10240;
constexpr int TPB    = 1024;
constexpr int ROWS   = 4;                 // batch rows per block
constexpr int FPT    = OUT_F / TPB;       // 10 features per thread
constexpr int NBINS  = 1024;              // per-row bins over [4,6), width 1/512
constexpr int NWAVES = TPB / 64;          // 16
constexpr int CAP    = 64;                // bracket-bin list capacity per row

static_assert(NBINS == 64 * 16, "wave scan assumes 16 bins per lane");

// LDS-only barrier: no vmcnt drain (the compiler's __syncthreads would
// drain the zero-store queue). All cross-thread deps at call sites are LDS.
__device__ __forceinline__ void bar_lds() {
  asm volatile("s_waitcnt lgkmcnt(0)" ::: "memory");
  __builtin_amdgcn_s_barrier();
}

// ---------------------------------------------------------------------------
// Kernel 1: extract sparse indices from dense W. One wave per W row.
// Emits indices ASCENDING (required for bit-exact fold-left downstream).
// ---------------------------------------------------------------------------
__global__ __launch_bounds__(256) void extract_idx(const float* __restrict__ W,
                                                   uint4* __restrict__ packed,
                                                   int out_f) {
  int row  = blockIdx.x * 4 + (threadIdx.x >> 6);
  int lane = threadIdx.x & 63;
  if (row >= out_f) return;

  const float* wr = W + (size_t)row * IN_F;
  unsigned long long masks[8];
#pragma unroll
  for (int c = 0; c < 8; ++c) {
    float v = wr[c * 64 + lane];
    masks[c] = __ballot(v != 0.0f);   // entries are exactly 0.0 or 1.0
  }
  if (lane == 0) {
    unsigned idx[6] = {IN_F, IN_F, IN_F, IN_F, IN_F, IN_F};  // pad -> zero slot
    int n = 0;
#pragma unroll
    for (int c = 0; c < 8; ++c) {
      unsigned long long m = masks[c];
      while (m && n < 6) {
        int b = __builtin_ctzll(m);
        idx[n++] = (unsigned)(c * 64 + b);
        m &= m - 1;
      }
    }
    uint4 r;
    r.x = idx[0] | (idx[1] << 16);
    r.y = idx[2] | (idx[3] << 16);
    r.z = idx[4] | (idx[5] << 16);
    r.w = (unsigned)n;
    packed[row] = r;
  }
}

// Serial fold of one row-component r (bit-identical to phase-1's fold).
__device__ __forceinline__ float row_val(const f4* in4, uint4 p, int r) {
  const float* b = (const float*)in4;
  float s = b[(p.x & 0xFFFFu) * 4 + r];
  s += b[(p.x >> 16) * 4 + r];
  s += b[(p.y & 0xFFFFu) * 4 + r];
  s += b[(p.y >> 16) * 4 + r];
  s += b[(p.z & 0xFFFFu) * 4 + r];
  s += b[(p.z >> 16) * 4 + r];
  return s;
}

// ---------------------------------------------------------------------------
// Kernel 2: 4 batch rows per block, 1024 threads.
// ---------------------------------------------------------------------------
__global__ __launch_bounds__(TPB, 4) void fly_hash(const float* __restrict__ inp,
                                                   const uint4* __restrict__ packed,
                                                   const int* __restrict__ kptr,
                                                   float* __restrict__ out) {
  __shared__ f4    in4[IN_F + 1];       // 8.2 KB; [IN_F] = zero slot for pads
  __shared__ int   hist[ROWS * NBINS];  // 16 KB
  __shared__ int   wsum[NWAVES];
  __shared__ int   sh_bstar[ROWS], sh_above[ROWS], sh_n[ROWS], sh_cnt[ROWS];
  __shared__ float sh_list[ROWS][CAP];
  __shared__ float sh_thr[ROWS];
  __shared__ int   sh_need[ROWS];       // 1 -> fallback binary search

  const int tid  = threadIdx.x;
  const int lane = tid & 63;
  const int wid  = tid >> 6;
  const int row0 = blockIdx.x * ROWS;
  const int k    = *kptr;               // hash_length (32)

  float* o0 = out + (size_t)(row0 + 0) * OUT_F;
  float* o1 = out + (size_t)(row0 + 1) * OUT_F;
  float* o2 = out + (size_t)(row0 + 2) * OUT_F;
  float* o3 = out + (size_t)(row0 + 3) * OUT_F;

  // --- (a) prefetch packed + staging loads (OLDEST in the vmcnt FIFO) ----
  uint4 rk[FPT];
#pragma unroll
  for (int i = 0; i < FPT; ++i) rk[i] = packed[tid + i * TPB];

  f4 sv = {0.0f, 0.0f, 0.0f, 0.0f};
  if (tid < IN_F) {
    const float* p = inp + (size_t)row0 * IN_F + tid;
    sv.x = p[0];
    sv.y = p[IN_F];
    sv.z = p[2 * IN_F];
    sv.w = p[3 * IN_F];
  }

  // --- (b) zero-stream: the dense output is 99.7% zeros; write them NOW --
  // (younger than all loads, so no load-wait ever drains these stores).
  // They stream to HBM under phases 1-4; nonzeros are patched at the end.
#pragma unroll
  for (int i = 0; i < FPT; ++i) {
    int f = tid + i * TPB;
    __builtin_nontemporal_store(0.0f, &o0[f]);
    __builtin_nontemporal_store(0.0f, &o1[f]);
    __builtin_nontemporal_store(0.0f, &o2[f]);
    __builtin_nontemporal_store(0.0f, &o3[f]);
  }

  // --- (c) stage 4 input rows transposed into LDS + init state -----------
  if (tid < IN_F) {
    in4[tid] = sv;                      // ds_write_b128 (waits loads only)
  } else if (tid == IN_F) {
    f4 z = {0.0f, 0.0f, 0.0f, 0.0f};
    in4[IN_F] = z;
  }
  if (tid < ROWS) { sh_bstar[tid] = -1; sh_cnt[tid] = 0; }
  for (int i = tid; i < ROWS * NBINS; i += TPB) hist[i] = 0;
  bar_lds();

  // --- phase 1: compute x (bit-exact serial fold-left) + histogram -------
  f4 x4[FPT];
#pragma unroll
  for (int i = 0; i < FPT; ++i) {
    uint4 r = rk[i];
    f4 s = in4[r.x & 0xFFFFu];          // ds_read_b128: 4 rows per gather
    s += in4[r.x >> 16];
    s += in4[r.y & 0xFFFFu];
    s += in4[r.y >> 16];
    s += in4[r.z & 0xFFFFu];
    s += in4[r.z >> 16];
    x4[i] = s;
#pragma unroll
    for (int rr = 0; rr < ROWS; ++rr) {
      float v = s[rr];
      if (v >= 4.0f) {                  // top-32 of 10240 ~ 4.8; bin >=4 only
        int b = (int)((v - 4.0f) * 512.0f);    // EXACT key (Sterbenz + pow2)
        b = b > NBINS - 1 ? NBINS - 1 : b;
        atomicAdd(&hist[rr * NBINS + b], 1);
      }
    }
  }
  bar_lds();

  // --- phase 2: wave-parallel bracket-bin search (wave r owns row r) -----
  if (wid < ROWS) {
    const int r = wid;
    const int base = r * NBINS + lane * 16;
    int csum = 0;
#pragma unroll
    for (int j = 0; j < 16; ++j) csum += hist[base + j];
    int s = csum;                       // inclusive suffix sum across lanes
#pragma unroll
    for (int off = 1; off < 64; off <<= 1) {
      int t = __shfl_down(s, off);
      if (lane + off < 64) s += t;
    }
    int s_next = __shfl_down(s, 1);     // suffix starting at lane+1
    if (lane == 63) s_next = 0;
    if (s >= k && s_next < k) {         // unique crossing chunk (if any)
      int acc = s_next;
      int bsel = lane * 16, abv = s_next;
      for (int b = lane * 16 + 15; b >= lane * 16; --b) {
        int h = hist[r * NBINS + b];
        if (acc + h >= k) { bsel = b; abv = acc; break; }
        acc += h;
      }
      sh_bstar[r] = bsel;
      sh_above[r] = abv;
      sh_n[r]     = hist[r * NBINS + bsel];
    }
  }
  bar_lds();

  // --- phase 3a: collect bracket-bin members into per-row lists ----------
  {
    const int b0 = sh_bstar[0], b1 = sh_bstar[1];
    const int b2 = sh_bstar[2], b3 = sh_bstar[3];
#pragma unroll
    for (int i = 0; i < FPT; ++i) {
      f4 s = x4[i];
#pragma unroll
      for (int rr = 0; rr < ROWS; ++rr) {
        float v = s[rr];
        int bb = (rr == 0) ? b0 : (rr == 1) ? b1 : (rr == 2) ? b2 : b3;
        if (v >= 4.0f) {
          int b = (int)((v - 4.0f) * 512.0f);
          b = b > NBINS - 1 ? NBINS - 1 : b;
          if (b == bb) {
            int p = atomicAdd(&sh_cnt[rr], 1);
            if (p < CAP) sh_list[rr][p] = v;
          }
        }
      }
    }
  }
  bar_lds();

  // --- phase 3b: wave r rank-selects the (k-above)-th largest ------------
  if (wid < ROWS) {
    const int r   = wid;
    const int bst = sh_bstar[r];
    const int n   = (bst >= 0) ? sh_n[r] : CAP + 1;
    if (bst >= 0 && n <= CAP && sh_cnt[r] <= CAP) {
      const int j = k - sh_above[r];            // 1 <= j <= n
      float vl = (lane < n) ? sh_list[r][lane] : -1.0f;
      int cgt = 0, cge = 0;
      for (int m = 0; m < n; ++m) {
        float u = sh_list[r][m];                // broadcast LDS read
        cgt += (u > vl);
        cge += (u >= vl);
      }
      if (lane < n && cgt < j && cge >= j) sh_thr[r] = vl;  // exact k-th bits
      if (lane == 0) sh_need[r] = 0;
    } else {
      if (lane == 0) sh_need[r] = 1;            // overflow / no bracket
    }
  }
  bar_lds();

  // --- phase 4: fallback (recomputes from LDS, never touches x4; rare) ---
#pragma unroll 1
  for (int r = 0; r < ROWS; ++r) {
    if (!sh_need[r]) continue;
    unsigned lo = 0u, hi = __float_as_uint(8.0f);
    while (lo < hi) {
      unsigned mid = lo + ((hi - lo + 1u) >> 1);
      float fm = __uint_as_float(mid);
      int c = 0;
      for (int i = 0; i < FPT; ++i) {
        uint4 p = packed[tid + i * TPB];
        c += (int)__popcll(__ballot(row_val(in4, p, r) >= fm));
      }
      if (lane == 0) wsum[wid] = c;
      __syncthreads();
      int tot = 0;
#pragma unroll
      for (int w = 0; w < NWAVES; ++w) tot += wsum[w];
      if (tot >= k) lo = mid; else hi = mid - 1u;
      __syncthreads();
    }
    if (tid == 0) sh_thr[r] = __uint_as_float(lo);
    __syncthreads();
  }
  const float t0 = sh_thr[0];
  const float t1 = sh_thr[1];
  const float t2 = sh_thr[2];
  const float t3 = sh_thr[3];

  // --- phase 5: sparse scatter of survivors (~32/row) --------------------
  // Own-lane zero-store -> own-lane value-store to the same address: order
  // by draining this wave's store queue (cheap: zeros drained under p1-4).
  asm volatile("s_waitcnt vmcnt(0)" ::: "memory");
#pragma unroll
  for (int i = 0; i < FPT; ++i) {
    int f = tid + i * TPB;
    f4 v = x4[i];
    if (v.x >= t0) o0[f] = v.x;
    if (v.y >= t1) o1[f] = v.y;
    if (v.z >= t2) o2[f] = v.z;
    if (v.w >= t3) o3[f] = v.w;
  }
}

// ---------------------------------------------------------------------------
extern "C" void kernel_launch(void* const* d_in, const int* in_sizes, int n_in,
                              void* d_out, int out_size, void* d_ws, size_t ws_size,
                              hipStream_t stream) {
  const float* inp = (const float*)d_in[0];
  const float* W   = (const float*)d_in[1];
  const int* kptr  = (const int*)d_in[2];
  float* out       = (float*)d_out;

  const int batch = in_sizes[0] / IN_F;   // 4096
  const int out_f = in_sizes[1] / IN_F;   // 10240

  uint4* packed = (uint4*)d_ws;           // 10240 * 16 B = 160 KB scratch

  hipLaunchKernelGGL(extract_idx, dim3((out_f + 3) / 4), dim3(256), 0, stream,
                     W, packed, out_f);
  hipLaunchKernelGGL(fly_hash, dim3(batch / ROWS), dim3(TPB), 0, stream,
                     inp, packed, kptr, out);
}

// Round 9
// 256.346 us; speedup vs baseline: 1.0772x; 1.0772x over previous
//
#include <hip/hip_runtime.h>

// FlyHash-style sparse projection + per-row exact top-k threshold.
//
// Round 21: ROWS 4->8 (grid 512, one 1024-thread block per CU per round,
// 2 rounds). Same total gather/store/VALU work, but per-CU the serial
// phase-chain overhead halves in structure: staging uses ALL 1024 threads
// (was 512), phases 2/3b use 8/16 waves (was 4/16), and rounds are clean
// single-block (no lockstep co-resident LDS contention). Everything inside
// the phases is champion-R12/R17 verbatim per row.
// VGPR discipline (hard constraint: 1024-thr block needs <=128 VGPR to be
// resident): rk loaded per-iteration (R17 measured prefetch == neutral),
// xa[10]+xb[10]=80 persisted, est peak ~110.
// Dead ends measured this session: chunking (R15/16/18: vmcnt-drain +
// spills), candidate-list select (R14: serial LDS loops 4.4e7 conflicts),
// zero-stream + lgkm barriers (R19/20: -39us, nt write-combine defeat),
// 512-thr co-residency (R13: same 16 waves/CU), rk prefetch (R17: +0.6).
// Bit-exactness (absmax 0, R2-R20): serial f32 fold-left ascending ==
// ref einsum accumulation; threshold = an actual x value's bit pattern;
// predicate v >= t (ties kept) == jnp.where(x >= thresh).

typedef float f4 __attribute__((ext_vector_type(4)));

constexpr int IN_F   = 512;
constexpr int OUT_F  = 10240;
constexpr int TPB    = 1024;
constexpr int ROWS   = 8;                 // batch rows per block (4+4 split)
constexpr int FPT    = OUT_F / TPB;       // 10 features per thread
constexpr int NBINS  = 1024;              // per-row bins over [4,6), width 1/512
constexpr int NWAVES = TPB / 64;          // 16
constexpr int CAP    = 64;                // bracket-bin list capacity per row

static_assert(NBINS == 64 * 16, "wave scan assumes 16 bins per lane");

// ---------------------------------------------------------------------------
// Kernel 1: extract sparse indices from dense W. One wave per W row.
// Emits indices ASCENDING (required for bit-exact fold-left downstream).
// ---------------------------------------------------------------------------
__global__ __launch_bounds__(256) void extract_idx(const float* __restrict__ W,
                                                   uint4* __restrict__ packed,
                                                   int out_f) {
  int row  = blockIdx.x * 4 + (threadIdx.x >> 6);
  int lane = threadIdx.x & 63;
  if (row >= out_f) return;

  const float* wr = W + (size_t)row * IN_F;
  unsigned long long masks[8];
#pragma unroll
  for (int c = 0; c < 8; ++c) {
    float v = wr[c * 64 + lane];
    masks[c] = __ballot(v != 0.0f);   // entries are exactly 0.0 or 1.0
  }
  if (lane == 0) {
    unsigned idx[6] = {IN_F, IN_F, IN_F, IN_F, IN_F, IN_F};  // pad -> zero slot
    int n = 0;
#pragma unroll
    for (int c = 0; c < 8; ++c) {
      unsigned long long m = masks[c];
      while (m && n < 6) {
        int b = __builtin_ctzll(m);
        idx[n++] = (unsigned)(c * 64 + b);
        m &= m - 1;
      }
    }
    uint4 r;
    r.x = idx[0] | (idx[1] << 16);
    r.y = idx[2] | (idx[3] << 16);
    r.z = idx[4] | (idx[5] << 16);
    r.w = (unsigned)n;
    packed[row] = r;
  }
}

// Serial fold of one row-component r (bit-identical to phase-1's fold).
__device__ __forceinline__ float row_val(const f4* in4, uint4 p, int r) {
  const float* b = (const float*)in4;
  float s = b[(p.x & 0xFFFFu) * 4 + r];
  s += b[(p.x >> 16) * 4 + r];
  s += b[(p.y & 0xFFFFu) * 4 + r];
  s += b[(p.y >> 16) * 4 + r];
  s += b[(p.z & 0xFFFFu) * 4 + r];
  s += b[(p.z >> 16) * 4 + r];
  return s;
}

// ---------------------------------------------------------------------------
// Kernel 2: 8 batch rows per block (two 4-row transposed LDS arrays),
// 1024 threads, xa[10]+xb[10] persisted (80 VGPR).
// ---------------------------------------------------------------------------
__global__ __launch_bounds__(TPB, 4) void fly_hash(const float* __restrict__ inp,
                                                   const uint4* __restrict__ packed,
                                                   const int* __restrict__ kptr,
                                                   float* __restrict__ out) {
  __shared__ f4    in4a[IN_F + 1];      // rows 0-3; [IN_F] = zero slot
  __shared__ f4    in4b[IN_F + 1];      // rows 4-7; [IN_F] = zero slot
  __shared__ int   hist[ROWS * NBINS];  // 32 KB
  __shared__ int   wsum[NWAVES];
  __shared__ int   sh_bstar[ROWS], sh_above[ROWS], sh_n[ROWS], sh_cnt[ROWS];
  __shared__ float sh_list[ROWS][CAP];
  __shared__ float sh_thr[ROWS];
  __shared__ int   sh_need[ROWS];       // 1 -> fallback binary search

  const int tid  = threadIdx.x;
  const int lane = tid & 63;
  const int wid  = tid >> 6;
  const int row0 = blockIdx.x * ROWS;
  const int k    = *kptr;               // hash_length (32)

  // --- stage 8 input rows transposed into LDS (all 1024 threads) --------
  {
    const int t = tid & 511;
    const float* p = inp + (size_t)(row0 + (tid >> 9) * 4) * IN_F + t;
    f4 v;
    v.x = p[0];
    v.y = p[IN_F];
    v.z = p[2 * IN_F];
    v.w = p[3 * IN_F];
    if (tid < 512) in4a[t] = v; else in4b[t] = v;   // ds_write_b128
  }
  if (tid == 0) {
    f4 z = {0.0f, 0.0f, 0.0f, 0.0f};
    in4a[IN_F] = z;
    in4b[IN_F] = z;
  }
  if (tid < ROWS) { sh_bstar[tid] = -1; sh_cnt[tid] = 0; }
  for (int i = tid; i < ROWS * NBINS; i += TPB) hist[i] = 0;
  __syncthreads();

  // --- phase 1: compute x (bit-exact serial fold-left) + histogram -------
  f4 xa[FPT], xb[FPT];
#pragma unroll
  for (int i = 0; i < FPT; ++i) {
    uint4 r = packed[tid + i * TPB];
    const unsigned i0 = r.x & 0xFFFFu, i1 = r.x >> 16;
    const unsigned i2 = r.y & 0xFFFFu, i3 = r.y >> 16;
    const unsigned i4 = r.z & 0xFFFFu, i5 = r.z >> 16;
    f4 sa = in4a[i0];                   // ds_read_b128: 4 rows per gather
    sa += in4a[i1];
    sa += in4a[i2];
    sa += in4a[i3];
    sa += in4a[i4];
    sa += in4a[i5];
    f4 sb = in4b[i0];
    sb += in4b[i1];
    sb += in4b[i2];
    sb += in4b[i3];
    sb += in4b[i4];
    sb += in4b[i5];
    xa[i] = sa;
    xb[i] = sb;
#pragma unroll
    for (int rr = 0; rr < 4; ++rr) {
      float v = sa[rr];
      if (v >= 4.0f) {                  // top-32 of 10240 ~ 4.8; bin >=4 only
        int b = (int)((v - 4.0f) * 512.0f);    // EXACT key (Sterbenz + pow2)
        b = b > NBINS - 1 ? NBINS - 1 : b;
        atomicAdd(&hist[rr * NBINS + b], 1);
      }
    }
#pragma unroll
    for (int rr = 0; rr < 4; ++rr) {
      float v = sb[rr];
      if (v >= 4.0f) {
        int b = (int)((v - 4.0f) * 512.0f);
        b = b > NBINS - 1 ? NBINS - 1 : b;
        atomicAdd(&hist[(rr + 4) * NBINS + b], 1);
      }
    }
  }
  __syncthreads();

  // --- phase 2: wave-parallel bracket-bin search (wave r owns row r) -----
  if (wid < ROWS) {
    const int r = wid;
    const int base = r * NBINS + lane * 16;
    int csum = 0;
#pragma unroll
    for (int j = 0; j < 16; ++j) csum += hist[base + j];
    int s = csum;                       // inclusive suffix sum across lanes
#pragma unroll
    for (int off = 1; off < 64; off <<= 1) {
      int t = __shfl_down(s, off);
      if (lane + off < 64) s += t;
    }
    int s_next = __shfl_down(s, 1);     // suffix starting at lane+1
    if (lane == 63) s_next = 0;
    if (s >= k && s_next < k) {         // unique crossing chunk (if any)
      int acc = s_next;
      int bsel = lane * 16, abv = s_next;
      for (int b = lane * 16 + 15; b >= lane * 16; --b) {
        int h = hist[r * NBINS + b];
        if (acc + h >= k) { bsel = b; abv = acc; break; }
        acc += h;
      }
      sh_bstar[r] = bsel;
      sh_above[r] = abv;
      sh_n[r]     = hist[r * NBINS + bsel];
    }
  }
  __syncthreads();

  // --- phase 3a: collect bracket-bin members into per-row lists ----------
  {
    const int b0 = sh_bstar[0], b1 = sh_bstar[1];
    const int b2 = sh_bstar[2], b3 = sh_bstar[3];
    const int b4 = sh_bstar[4], b5 = sh_bstar[5];
    const int b6 = sh_bstar[6], b7 = sh_bstar[7];
#pragma unroll
    for (int i = 0; i < FPT; ++i) {
      f4 sa = xa[i];
#pragma unroll
      for (int rr = 0; rr < 4; ++rr) {
        float v = sa[rr];
        int bb = (rr == 0) ? b0 : (rr == 1) ? b1 : (rr == 2) ? b2 : b3;
        if (v >= 4.0f) {
          int b = (int)((v - 4.0f) * 512.0f);
          b = b > NBINS - 1 ? NBINS - 1 : b;
          if (b == bb) {
            int p = atomicAdd(&sh_cnt[rr], 1);
            if (p < CAP) sh_list[rr][p] = v;
          }
        }
      }
      f4 sb = xb[i];
#pragma unroll
      for (int rr = 0; rr < 4; ++rr) {
        float v = sb[rr];
        int bb = (rr == 0) ? b4 : (rr == 1) ? b5 : (rr == 2) ? b6 : b7;
        if (v >= 4.0f) {
          int b = (int)((v - 4.0f) * 512.0f);
          b = b > NBINS - 1 ? NBINS - 1 : b;
          if (b == bb) {
            int p = atomicAdd(&sh_cnt[rr + 4], 1);
            if (p < CAP) sh_list[rr + 4][p] = v;
          }
        }
      }
    }
  }
  __syncthreads();

  // --- phase 3b: wave r rank-selects the (k-above)-th largest ------------
  if (wid < ROWS) {
    const int r   = wid;
    const int bst = sh_bstar[r];
    const int n   = (bst >= 0) ? sh_n[r] : CAP + 1;
    if (bst >= 0 && n <= CAP && sh_cnt[r] <= CAP) {
      const int j = k - sh_above[r];            // 1 <= j <= n
      float vl = (lane < n) ? sh_list[r][lane] : -1.0f;
      int cgt = 0, cge = 0;
      for (int m = 0; m < n; ++m) {
        float u = sh_list[r][m];                // broadcast LDS read
        cgt += (u > vl);
        cge += (u >= vl);
      }
      if (lane < n && cgt < j && cge >= j) sh_thr[r] = vl;  // exact k-th bits
      if (lane == 0) sh_need[r] = 0;
    } else {
      if (lane == 0) sh_need[r] = 1;            // overflow / no bracket
    }
  }
  __syncthreads();

  // --- phase 4: fallback (recomputes from LDS, never touches xa/xb; rare) -
#pragma unroll 1
  for (int r = 0; r < ROWS; ++r) {
    if (!sh_need[r]) continue;
    const f4* inx = (r < 4) ? in4a : in4b;
    const int rc  = r & 3;
    unsigned lo = 0u, hi = __float_as_uint(8.0f);
    while (lo < hi) {
      unsigned mid = lo + ((hi - lo + 1u) >> 1);
      float fm = __uint_as_float(mid);
      int c = 0;
      for (int i = 0; i < FPT; ++i) {
        uint4 p = packed[tid + i * TPB];
        c += (int)__popcll(__ballot(row_val(inx, p, rc) >= fm));
      }
      if (lane == 0) wsum[wid] = c;
      __syncthreads();
      int tot = 0;
#pragma unroll
      for (int w = 0; w < NWAVES; ++w) tot += wsum[w];
      if (tot >= k) lo = mid; else hi = mid - 1u;
      __syncthreads();
    }
    if (tid == 0) sh_thr[r] = __uint_as_float(lo);
    __syncthreads();
  }
  const float t0 = sh_thr[0];
  const float t1 = sh_thr[1];
  const float t2 = sh_thr[2];
  const float t3 = sh_thr[3];
  const float t4 = sh_thr[4];
  const float t5 = sh_thr[5];
  const float t6 = sh_thr[6];
  const float t7 = sh_thr[7];

  // --- phase 5: thresholded writes, 8 coalesced nontemporal streams ------
  float* o0 = out + (size_t)(row0 + 0) * OUT_F;
  float* o1 = out + (size_t)(row0 + 1) * OUT_F;
  float* o2 = out + (size_t)(row0 + 2) * OUT_F;
  float* o3 = out + (size_t)(row0 + 3) * OUT_F;
  float* o4 = out + (size_t)(row0 + 4) * OUT_F;
  float* o5 = out + (size_t)(row0 + 5) * OUT_F;
  float* o6 = out + (size_t)(row0 + 6) * OUT_F;
  float* o7 = out + (size_t)(row0 + 7) * OUT_F;
#pragma unroll
  for (int i = 0; i < FPT; ++i) {
    int f = tid + i * TPB;
    f4 va = xa[i];
    f4 vb = xb[i];
    __builtin_nontemporal_store((va.x >= t0) ? va.x : 0.0f, &o0[f]);
    __builtin_nontemporal_store((va.y >= t1) ? va.y : 0.0f, &o1[f]);
    __builtin_nontemporal_store((va.z >= t2) ? va.z : 0.0f, &o2[f]);
    __builtin_nontemporal_store((va.w >= t3) ? va.w : 0.0f, &o3[f]);
    __builtin_nontemporal_store((vb.x >= t4) ? vb.x : 0.0f, &o4[f]);
    __builtin_nontemporal_store((vb.y >= t5) ? vb.y : 0.0f, &o5[f]);
    __builtin_nontemporal_store((vb.z >= t6) ? vb.z : 0.0f, &o6[f]);
    __builtin_nontemporal_store((vb.w >= t7) ? vb.w : 0.0f, &o7[f]);
  }
}

// ---------------------------------------------------------------------------
extern "C" void kernel_launch(void* const* d_in, const int* in_sizes, int n_in,
                              void* d_out, int out_size, void* d_ws, size_t ws_size,
                              hipStream_t stream) {
  const float* inp = (const float*)d_in[0];
  const float* W   = (const float*)d_in[1];
  const int* kptr  = (const int*)d_in[2];
  float* out       = (float*)d_out;

  const int batch = in_sizes[0] / IN_F;   // 4096
  const int out_f = in_sizes[1] / IN_F;   // 10240

  uint4* packed = (uint4*)d_ws;           // 10240 * 16 B = 160 KB scratch

  hipLaunchKernelGGL(extract_idx, dim3((out_f + 3) / 4), dim3(256), 0, stream,
                     W, packed, out_f);
  hipLaunchKernelGGL(fly_hash, dim3(batch / ROWS), dim3(TPB), 0, stream,
                     inp, packed, kptr, out);
}

// Round 10
// 248.414 us; speedup vs baseline: 1.1116x; 1.0319x over previous
//
#include <hip/hip_runtime.h>

// FlyHash-style sparse projection + per-row exact top-k threshold.
//
// Round 22 = R17 champion verbatim (TPB=1024, grid=1024, ROWS=4, FPT=10,
// rk prefetch, 1024-bin hist + wave bracket scan + list select + exact
// fallback, __launch_bounds__(1024,4), nontemporal stores) with ONE change:
// histogram/binning cutoff raised 4.0 -> 4.5. LDS-pipe decomposition from
// the session's clean captures: ~19us b128-gather base + ~13us bank
// conflicts (random balls-in-bins, irreducible) + ~6us hist atomics + ~2.5us
// staging per CU. The atomics are the only removable term: cutoff 4.5 cuts
// active-lane atomics 12% -> ~1.6% (~4900 -> ~640 per block).
// Correctness is EXACT, not probabilistic: if a row's k-th value < 4.5
// (P ~ 1e-23; mean count above 4.5 is ~157), no crossing bin exists ->
// sh_bstar stays -1 -> the exact binary-search fallback computes the
// bit-exact threshold. Bin key stays exact: v-4.5 is Sterbenz-exact on
// [4.5, 6.5), *512 and floor exact; clamp handles v >= 6.5. Phase 3a uses
// the identical mapping, so bracket members are found consistently.
// Dead ends this session (all measured): chunking x3 (vmcnt-drain/spills),
// candidate-list select (serial LDS loops), zero-stream + lgkm barriers
// (nt write-combine defeat), 512-thr co-residency (same 16 waves/CU),
// ROWS=8 (lost co-residency stagger), MFMA (arithmetic: 3x exact-split
// dense GEMM = 80-143us > 78us sparse gather).
// Bit-exactness (absmax 0, R2-R21): serial f32 fold-left ascending ==
// ref einsum accumulation; threshold = an actual x value's bit pattern.

typedef float f4 __attribute__((ext_vector_type(4)));

constexpr int IN_F   = 512;
constexpr int OUT_F  = 10240;
constexpr int TPB    = 1024;
constexpr int ROWS   = 4;                 // batch rows per block
constexpr int FPT    = OUT_F / TPB;       // 10 features per thread
constexpr int NBINS  = 1024;              // per-row bins over [4.5,6.5), 1/512
constexpr int NWAVES = TPB / 64;          // 16
constexpr int CAP    = 64;                // bracket-bin list capacity per row
constexpr float BCUT = 4.5f;              // binning cutoff (exact fallback
                                          // covers the ~1e-23 miss case)

static_assert(NBINS == 64 * 16, "wave scan assumes 16 bins per lane");

// ---------------------------------------------------------------------------
// Kernel 1: extract sparse indices from dense W. One wave per W row.
// Emits indices ASCENDING (required for bit-exact fold-left downstream).
// ---------------------------------------------------------------------------
__global__ __launch_bounds__(256) void extract_idx(const float* __restrict__ W,
                                                   uint4* __restrict__ packed,
                                                   int out_f) {
  int row  = blockIdx.x * 4 + (threadIdx.x >> 6);
  int lane = threadIdx.x & 63;
  if (row >= out_f) return;

  const float* wr = W + (size_t)row * IN_F;
  unsigned long long masks[8];
#pragma unroll
  for (int c = 0; c < 8; ++c) {
    float v = wr[c * 64 + lane];
    masks[c] = __ballot(v != 0.0f);   // entries are exactly 0.0 or 1.0
  }
  if (lane == 0) {
    unsigned idx[6] = {IN_F, IN_F, IN_F, IN_F, IN_F, IN_F};  // pad -> zero slot
    int n = 0;
#pragma unroll
    for (int c = 0; c < 8; ++c) {
      unsigned long long m = masks[c];
      while (m && n < 6) {
        int b = __builtin_ctzll(m);
        idx[n++] = (unsigned)(c * 64 + b);
        m &= m - 1;
      }
    }
    uint4 r;
    r.x = idx[0] | (idx[1] << 16);
    r.y = idx[2] | (idx[3] << 16);
    r.z = idx[4] | (idx[5] << 16);
    r.w = (unsigned)n;
    packed[row] = r;
  }
}

// Serial fold of one row-component r (bit-identical to phase-1's fold).
__device__ __forceinline__ float row_val(const f4* in4, uint4 p, int r) {
  const float* b = (const float*)in4;
  float s = b[(p.x & 0xFFFFu) * 4 + r];
  s += b[(p.x >> 16) * 4 + r];
  s += b[(p.y & 0xFFFFu) * 4 + r];
  s += b[(p.y >> 16) * 4 + r];
  s += b[(p.z & 0xFFFFu) * 4 + r];
  s += b[(p.z >> 16) * 4 + r];
  return s;
}

// ---------------------------------------------------------------------------
// Kernel 2: 4 batch rows per block, 1024 threads, x4[10] persisted (40 VGPR)
// + rk[10] prefetch (dies as x4 is born).
// ---------------------------------------------------------------------------
__global__ __launch_bounds__(TPB, 4) void fly_hash(const float* __restrict__ inp,
                                                   const uint4* __restrict__ packed,
                                                   const int* __restrict__ kptr,
                                                   float* __restrict__ out) {
  __shared__ f4    in4[IN_F + 1];       // 8.2 KB; [IN_F] = zero slot for pads
  __shared__ int   hist[ROWS * NBINS];  // 16 KB
  __shared__ int   wsum[NWAVES];
  __shared__ int   sh_bstar[ROWS], sh_above[ROWS], sh_n[ROWS], sh_cnt[ROWS];
  __shared__ float sh_list[ROWS][CAP];
  __shared__ float sh_thr[ROWS];
  __shared__ int   sh_need[ROWS];       // 1 -> fallback binary search

  const int tid  = threadIdx.x;
  const int lane = tid & 63;
  const int wid  = tid >> 6;
  const int row0 = blockIdx.x * ROWS;
  const int k    = *kptr;               // hash_length (32)

  // --- stage 4 input rows transposed into LDS ---------------------------
  if (tid < IN_F) {
    const float* p = inp + (size_t)row0 * IN_F + tid;
    f4 v;
    v.x = p[0];
    v.y = p[IN_F];
    v.z = p[2 * IN_F];
    v.w = p[3 * IN_F];
    in4[tid] = v;                       // ds_write_b128, conflict-free
  } else if (tid == IN_F) {
    f4 z = {0.0f, 0.0f, 0.0f, 0.0f};
    in4[IN_F] = z;
  }
  if (tid < ROWS) { sh_bstar[tid] = -1; sh_cnt[tid] = 0; }
  for (int i = tid; i < ROWS * NBINS; i += TPB) hist[i] = 0;
  __syncthreads();

  // --- phase 1: prefetch packed, then gather/fold (bit-exact) + histogram -
  uint4 rk[FPT];
#pragma unroll
  for (int i = 0; i < FPT; ++i) rk[i] = packed[tid + i * TPB];

  f4 x4[FPT];
#pragma unroll
  for (int i = 0; i < FPT; ++i) {
    uint4 r = rk[i];
    f4 s = in4[r.x & 0xFFFFu];          // ds_read_b128: 4 rows per gather
    s += in4[r.x >> 16];
    s += in4[r.y & 0xFFFFu];
    s += in4[r.y >> 16];
    s += in4[r.z & 0xFFFFu];
    s += in4[r.z >> 16];
    x4[i] = s;
#pragma unroll
    for (int rr = 0; rr < ROWS; ++rr) {
      float v = s[rr];
      if (v >= BCUT) {                  // ~1.6% of values (was 12% at 4.0)
        int b = (int)((v - BCUT) * 512.0f);    // EXACT key (Sterbenz + pow2)
        b = b > NBINS - 1 ? NBINS - 1 : b;
        atomicAdd(&hist[rr * NBINS + b], 1);
      }
    }
  }
  __syncthreads();

  // --- phase 2: wave-parallel bracket-bin search (wave r owns row r) -----
  // Lane L sums bins [16L, 16L+16); 6-step shfl suffix scan; crossing lane
  // walks its 16 bins descending to the exact bin. No internal barriers.
  if (wid < ROWS) {
    const int r = wid;
    const int base = r * NBINS + lane * 16;
    int csum = 0;
#pragma unroll
    for (int j = 0; j < 16; ++j) csum += hist[base + j];
    int s = csum;                       // inclusive suffix sum across lanes
#pragma unroll
    for (int off = 1; off < 64; off <<= 1) {
      int t = __shfl_down(s, off);
      if (lane + off < 64) s += t;
    }
    int s_next = __shfl_down(s, 1);     // suffix starting at lane+1
    if (lane == 63) s_next = 0;
    if (s >= k && s_next < k) {         // unique crossing chunk (if any)
      int acc = s_next;
      int bsel = lane * 16, abv = s_next;
      for (int b = lane * 16 + 15; b >= lane * 16; --b) {
        int h = hist[r * NBINS + b];
        if (acc + h >= k) { bsel = b; abv = acc; break; }
        acc += h;
      }
      sh_bstar[r] = bsel;
      sh_above[r] = abv;
      sh_n[r]     = hist[r * NBINS + bsel];
    }
  }
  __syncthreads();

  // --- phase 3a: collect bracket-bin members into per-row lists ----------
  {
    const int b0 = sh_bstar[0], b1 = sh_bstar[1];
    const int b2 = sh_bstar[2], b3 = sh_bstar[3];
#pragma unroll
    for (int i = 0; i < FPT; ++i) {
      f4 s = x4[i];
#pragma unroll
      for (int rr = 0; rr < ROWS; ++rr) {
        float v = s[rr];
        int bb = (rr == 0) ? b0 : (rr == 1) ? b1 : (rr == 2) ? b2 : b3;
        if (v >= BCUT) {
          int b = (int)((v - BCUT) * 512.0f);  // same exact mapping as hist
          b = b > NBINS - 1 ? NBINS - 1 : b;
          if (b == bb) {
            int p = atomicAdd(&sh_cnt[rr], 1);
            if (p < CAP) sh_list[rr][p] = v;
          }
        }
      }
    }
  }
  __syncthreads();

  // --- phase 3b: wave r rank-selects the (k-above)-th largest in its list -
  if (wid < ROWS) {
    const int r   = wid;
    const int bst = sh_bstar[r];
    const int n   = (bst >= 0) ? sh_n[r] : CAP + 1;
    if (bst >= 0 && n <= CAP && sh_cnt[r] <= CAP) {
      const int j = k - sh_above[r];            // 1 <= j <= n
      float vl = (lane < n) ? sh_list[r][lane] : -1.0f;
      int cgt = 0, cge = 0;
      for (int m = 0; m < n; ++m) {
        float u = sh_list[r][m];                // broadcast LDS read
        cgt += (u > vl);
        cge += (u >= vl);
      }
      if (lane < n && cgt < j && cge >= j) sh_thr[r] = vl;  // exact k-th bits
      if (lane == 0) sh_need[r] = 0;
    } else {
      if (lane == 0) sh_need[r] = 1;            // overflow / no bracket
    }
  }
  __syncthreads();

  // --- phase 4: fallback (recomputes from LDS, never touches x4; rare) ---
#pragma unroll 1
  for (int r = 0; r < ROWS; ++r) {
    if (!sh_need[r]) continue;
    unsigned lo = 0u, hi = __float_as_uint(8.0f);
    while (lo < hi) {
      unsigned mid = lo + ((hi - lo + 1u) >> 1);
      float fm = __uint_as_float(mid);
      int c = 0;
      for (int i = 0; i < FPT; ++i) {
        uint4 p = packed[tid + i * TPB];
        c += (int)__popcll(__ballot(row_val(in4, p, r) >= fm));
      }
      if (lane == 0) wsum[wid] = c;
      __syncthreads();
      int tot = 0;
#pragma unroll
      for (int w = 0; w < NWAVES; ++w) tot += wsum[w];
      if (tot >= k) lo = mid; else hi = mid - 1u;
      __syncthreads();
    }
    if (tid == 0) sh_thr[r] = __uint_as_float(lo);
    __syncthreads();
  }
  const float t0 = sh_thr[0];
  const float t1 = sh_thr[1];
  const float t2 = sh_thr[2];
  const float t3 = sh_thr[3];

  // --- phase 5: thresholded writes, 4 coalesced nontemporal streams ------
  float* o0 = out + (size_t)(row0 + 0) * OUT_F;
  float* o1 = out + (size_t)(row0 + 1) * OUT_F;
  float* o2 = out + (size_t)(row0 + 2) * OUT_F;
  float* o3 = out + (size_t)(row0 + 3) * OUT_F;
#pragma unroll
  for (int i = 0; i < FPT; ++i) {
    int f = tid + i * TPB;
    f4 v = x4[i];
    __builtin_nontemporal_store((v.x >= t0) ? v.x : 0.0f, &o0[f]);
    __builtin_nontemporal_store((v.y >= t1) ? v.y : 0.0f, &o1[f]);
    __builtin_nontemporal_store((v.z >= t2) ? v.z : 0.0f, &o2[f]);
    __builtin_nontemporal_store((v.w >= t3) ? v.w : 0.0f, &o3[f]);
  }
}

// ---------------------------------------------------------------------------
extern "C" void kernel_launch(void* const* d_in, const int* in_sizes, int n_in,
                              void* d_out, int out_size, void* d_ws, size_t ws_size,
                              hipStream_t stream) {
  const float* inp = (const float*)d_in[0];
  const float* W   = (const float*)d_in[1];
  const int* kptr  = (const int*)d_in[2];
  float* out       = (float*)d_out;

  const int batch = in_sizes[0] / IN_F;   // 4096
  const int out_f = in_sizes[1] / IN_F;   // 10240

  uint4* packed = (uint4*)d_ws;           // 10240 * 16 B = 160 KB scratch

  hipLaunchKernelGGL(extract_idx, dim3((out_f + 3) / 4), dim3(256), 0, stream,
                     W, packed, out_f);
  hipLaunchKernelGGL(fly_hash, dim3(batch / ROWS), dim3(TPB), 0, stream,
                     inp, packed, kptr, out);
}